// Round 1
// baseline (581.604 us; speedup 1.0000x reference)
//
#include <hip/hip_runtime.h>
#include <hip/hip_bf16.h>

// COO SpMM: out[r,:] = sum_{e: row[e]==r} values[e] * x[col[e],:]
// N=50000 nodes, NNZ=1.6M, F=256 fp32.
// Strategy: on-device CSR build (histogram -> scan -> scatter), then
// atomic-free SpMM with one wave per row, float4 per lane (64 lanes * 4 = 256).

#define FEAT 256
#define SCAN_CHUNK 2048   // 256 threads * 8 items

__global__ void zero_counts_kernel(int* deg, int n) {
    int i = blockIdx.x * blockDim.x + threadIdx.x;
    if (i < n) deg[i] = 0;
}

__global__ void hist_kernel(const int* __restrict__ row, int* __restrict__ deg, int nnz) {
    int stride = gridDim.x * blockDim.x;
    for (int e = blockIdx.x * blockDim.x + threadIdx.x; e < nnz; e += stride) {
        atomicAdd(&deg[row[e]], 1);
    }
}

// Per-chunk exclusive scan: rowstart[i] = exclusive-prefix within chunk.
// partials[b] = chunk total.
__global__ __launch_bounds__(256) void scan_chunks_kernel(const int* __restrict__ deg,
                                                          int* __restrict__ rowstart,
                                                          int* __restrict__ partials, int n) {
    __shared__ int s[256];
    const int tid = threadIdx.x;
    const int base = blockIdx.x * SCAN_CHUNK + tid * 8;
    int items[8];
    int sum = 0;
    #pragma unroll
    for (int j = 0; j < 8; ++j) {
        int v = (base + j < n) ? deg[base + j] : 0;
        items[j] = sum;         // exclusive within thread
        sum += v;
    }
    s[tid] = sum;
    __syncthreads();
    // Hillis-Steele inclusive scan over 256 thread sums
    for (int off = 1; off < 256; off <<= 1) {
        int t = (tid >= off) ? s[tid - off] : 0;
        __syncthreads();
        s[tid] += t;
        __syncthreads();
    }
    int thread_prefix = s[tid] - sum;  // exclusive across threads
    if (tid == 255) partials[blockIdx.x] = s[255];
    #pragma unroll
    for (int j = 0; j < 8; ++j) {
        if (base + j < n) rowstart[base + j] = items[j] + thread_prefix;
    }
}

__global__ void scan_partials_kernel(int* partials, int nb) {
    if (blockIdx.x == 0 && threadIdx.x == 0) {
        int run = 0;
        for (int i = 0; i < nb; ++i) { int v = partials[i]; partials[i] = run; run += v; }
    }
}

__global__ void finalize_scan_kernel(int* __restrict__ rowstart, const int* __restrict__ partials,
                                     int* __restrict__ cursor, int n, int nnz) {
    int i = blockIdx.x * blockDim.x + threadIdx.x;
    if (i < n) {
        int v = rowstart[i] + partials[i / SCAN_CHUNK];
        rowstart[i] = v;
        cursor[i] = v;
    }
    if (i == 0) rowstart[n] = nnz;
}

__global__ void scatter_kernel(const int* __restrict__ row, int* __restrict__ cursor,
                               int* __restrict__ eperm, int nnz) {
    int stride = gridDim.x * blockDim.x;
    for (int e = blockIdx.x * blockDim.x + threadIdx.x; e < nnz; e += stride) {
        int p = atomicAdd(&cursor[row[e]], 1);
        eperm[p] = e;
    }
}

// One 64-lane wave per row; lane owns 4 features (float4). Edge metadata is
// loaded lane-parallel (64 edges per batch) then broadcast via __shfl so the
// x-row gathers across edges are independent and pipeline.
__global__ __launch_bounds__(256) void spmm_kernel(const float* __restrict__ x,
                                                   const float* __restrict__ vals,
                                                   const int* __restrict__ col,
                                                   const int* __restrict__ rowstart,
                                                   const int* __restrict__ eperm,
                                                   float* __restrict__ out, int n) {
    const int wave = threadIdx.x >> 6;
    const int lane = threadIdx.x & 63;
    const int r = blockIdx.x * 4 + wave;
    if (r >= n) return;
    const int s = rowstart[r];
    const int e = rowstart[r + 1];
    const float4* __restrict__ xv = (const float4*)x;
    float4 acc = make_float4(0.f, 0.f, 0.f, 0.f);
    for (int k0 = s; k0 < e; k0 += 64) {
        int cnt = e - k0; if (cnt > 64) cnt = 64;
        float myv = 0.f; int myc = 0;
        if (lane < cnt) {
            int ed = eperm[k0 + lane];
            myv = vals[ed];
            myc = col[ed];
        }
        for (int j = 0; j < cnt; ++j) {
            float v = __shfl(myv, j);
            int   c = __shfl(myc, j);
            float4 xx = xv[c * 64 + lane];
            acc.x += v * xx.x;
            acc.y += v * xx.y;
            acc.z += v * xx.z;
            acc.w += v * xx.w;
        }
    }
    ((float4*)out)[r * 64 + lane] = acc;
}

extern "C" void kernel_launch(void* const* d_in, const int* in_sizes, int n_in,
                              void* d_out, int out_size, void* d_ws, size_t ws_size,
                              hipStream_t stream) {
    const float* x    = (const float*)d_in[0];
    const float* vals = (const float*)d_in[1];
    const int*   row  = (const int*)d_in[2];
    const int*   col  = (const int*)d_in[3];
    float* out = (float*)d_out;

    const int nnz = in_sizes[1];
    const int n   = out_size / FEAT;

    // workspace layout (ints)
    int* deg      = (int*)d_ws;            // n
    int* rowstart = deg + n;               // n + 1
    int* cursor   = rowstart + (n + 1);    // n
    int* partials = cursor + n;            // up to 64
    int* eperm    = partials + 64;         // nnz

    const int nb = (n + SCAN_CHUNK - 1) / SCAN_CHUNK;

    zero_counts_kernel<<<(n + 255) / 256, 256, 0, stream>>>(deg, n);
    hist_kernel<<<2048, 256, 0, stream>>>(row, deg, nnz);
    scan_chunks_kernel<<<nb, 256, 0, stream>>>(deg, rowstart, partials, n);
    scan_partials_kernel<<<1, 64, 0, stream>>>(partials, nb);
    finalize_scan_kernel<<<(n + 255) / 256, 256, 0, stream>>>(rowstart, partials, cursor, n, nnz);
    scatter_kernel<<<2048, 256, 0, stream>>>(row, cursor, eperm, nnz);
    spmm_kernel<<<(n + 3) / 4, 256, 0, stream>>>(x, vals, col, rowstart, eperm, out, n);
}

// Round 2
// 361.903 us; speedup vs baseline: 1.6071x; 1.6071x over previous
//
#include <hip/hip_runtime.h>
#include <hip/hip_bf16.h>

// COO SpMM: out[r,:] = sum_{e: row[e]==r} values[e] * x[col[e],:]
// N=50000, NNZ=1.6M, F=256 fp32 out.
// Pipeline: hist(+rank) -> chunk scan -> finalize(+partials reduce) ->
// atomic-free scatter of (col,val) pairs into CSR order -> wave-per-row SpMM
// gathering a bf16 copy of x (halves the dominant gather traffic), fp32 accum.

#define FEAT 256
#define SCAN_CHUNK 2048   // 256 threads * 8 items

static __device__ __forceinline__ unsigned short f2bf(float f) {
    unsigned int u = __float_as_uint(f);
    u += 0x7FFF + ((u >> 16) & 1);          // round-to-nearest-even
    return (unsigned short)(u >> 16);
}
static __device__ __forceinline__ float bf2f(unsigned short h) {
    return __uint_as_float(((unsigned int)h) << 16);
}

// ---------------- shared pipeline kernels ----------------

__global__ void convx_kernel(const float4* __restrict__ x, ushort4* __restrict__ xh, int n4) {
    int stride = gridDim.x * blockDim.x;
    for (int i = blockIdx.x * blockDim.x + threadIdx.x; i < n4; i += stride) {
        float4 v = x[i];
        ushort4 o;
        o.x = f2bf(v.x); o.y = f2bf(v.y); o.z = f2bf(v.z); o.w = f2bf(v.w);
        xh[i] = o;
    }
}

__global__ void hist_rank_kernel(const int* __restrict__ row, int* __restrict__ deg,
                                 int* __restrict__ rank, int nnz) {
    int stride = gridDim.x * blockDim.x;
    for (int e = blockIdx.x * blockDim.x + threadIdx.x; e < nnz; e += stride) {
        rank[e] = atomicAdd(&deg[row[e]], 1);
    }
}

// Per-chunk exclusive scan: rowstart[i] = exclusive prefix within chunk; partials[b] = chunk sum.
__global__ __launch_bounds__(256) void scan_chunks_kernel(const int* __restrict__ deg,
                                                          int* __restrict__ rowstart,
                                                          int* __restrict__ partials, int n) {
    __shared__ int s[256];
    const int tid = threadIdx.x;
    const int base = blockIdx.x * SCAN_CHUNK + tid * 8;
    int items[8];
    int sum = 0;
    #pragma unroll
    for (int j = 0; j < 8; ++j) {
        int v = (base + j < n) ? deg[base + j] : 0;
        items[j] = sum;
        sum += v;
    }
    s[tid] = sum;
    __syncthreads();
    for (int off = 1; off < 256; off <<= 1) {
        int t = (tid >= off) ? s[tid - off] : 0;
        __syncthreads();
        s[tid] += t;
        __syncthreads();
    }
    int thread_prefix = s[tid] - sum;
    if (tid == 255) partials[blockIdx.x] = s[255];
    #pragma unroll
    for (int j = 0; j < 8; ++j) {
        if (base + j < n) rowstart[base + j] = items[j] + thread_prefix;
    }
}

// Adds the cross-chunk prefix (reduced inline from partials) to each rowstart.
__global__ __launch_bounds__(256) void finalize_scan_kernel(int* __restrict__ rowstart,
                                                            const int* __restrict__ partials,
                                                            int n, int nnz) {
    __shared__ int sprefix;
    const int cb = (int)((blockIdx.x * 256u) / SCAN_CHUNK);   // chunk of this block
    if (threadIdx.x < 64) {
        int v = (threadIdx.x < cb) ? partials[threadIdx.x] : 0;
        #pragma unroll
        for (int off = 32; off; off >>= 1) v += __shfl_down(v, off);
        if (threadIdx.x == 0) sprefix = v;
    }
    __syncthreads();
    int i = blockIdx.x * 256 + threadIdx.x;
    if (i < n) rowstart[i] += sprefix;
    if (i == 0) rowstart[n] = nnz;
}

// Atomic-free scatter: CSR position = rowstart[row] + rank. Packs (col, val) so
// the SpMM reads edge metadata fully coalesced.
__global__ void scatter_pack_kernel(const int* __restrict__ row, const int* __restrict__ rank,
                                    const int* __restrict__ col, const float* __restrict__ vals,
                                    const int* __restrict__ rowstart, int2* __restrict__ pack,
                                    int nnz) {
    int stride = gridDim.x * blockDim.x;
    for (int e = blockIdx.x * blockDim.x + threadIdx.x; e < nnz; e += stride) {
        int p = rowstart[row[e]] + rank[e];
        pack[p] = make_int2(col[e], __float_as_int(vals[e]));
    }
}

// One 64-lane wave per row, lane owns 4 features. bf16 gather, fp32 accumulate.
__global__ __launch_bounds__(256) void spmm_bf16_kernel(const ushort4* __restrict__ xh,
                                                        const int2* __restrict__ pack,
                                                        const int* __restrict__ rowstart,
                                                        float* __restrict__ out, int n) {
    const int wave = threadIdx.x >> 6;
    const int lane = threadIdx.x & 63;
    const int r = blockIdx.x * 4 + wave;
    if (r >= n) return;
    const int s = rowstart[r];
    const int e = rowstart[r + 1];
    float4 acc = make_float4(0.f, 0.f, 0.f, 0.f);
    for (int k0 = s; k0 < e; k0 += 64) {
        int cnt = e - k0; if (cnt > 64) cnt = 64;
        float myv = 0.f; int myc = 0;
        if (lane < cnt) {
            int2 pr = pack[k0 + lane];
            myc = pr.x;
            myv = __int_as_float(pr.y);
        }
        for (int j = 0; j < cnt; ++j) {
            float v = __shfl(myv, j);
            int   c = __shfl(myc, j);
            ushort4 h = xh[c * 64 + lane];
            acc.x += v * bf2f(h.x);
            acc.y += v * bf2f(h.y);
            acc.z += v * bf2f(h.z);
            acc.w += v * bf2f(h.w);
        }
    }
    ((float4*)out)[r * 64 + lane] = acc;
}

// fp32-gather variant (fallback when ws can't hold the bf16 copy of x).
__global__ __launch_bounds__(256) void spmm_f32_kernel(const float4* __restrict__ xv,
                                                       const int2* __restrict__ pack,
                                                       const int* __restrict__ rowstart,
                                                       float* __restrict__ out, int n) {
    const int wave = threadIdx.x >> 6;
    const int lane = threadIdx.x & 63;
    const int r = blockIdx.x * 4 + wave;
    if (r >= n) return;
    const int s = rowstart[r];
    const int e = rowstart[r + 1];
    float4 acc = make_float4(0.f, 0.f, 0.f, 0.f);
    for (int k0 = s; k0 < e; k0 += 64) {
        int cnt = e - k0; if (cnt > 64) cnt = 64;
        float myv = 0.f; int myc = 0;
        if (lane < cnt) {
            int2 pr = pack[k0 + lane];
            myc = pr.x;
            myv = __int_as_float(pr.y);
        }
        for (int j = 0; j < cnt; ++j) {
            float v = __shfl(myv, j);
            int   c = __shfl(myc, j);
            float4 xx = xv[c * 64 + lane];
            acc.x += v * xx.x;
            acc.y += v * xx.y;
            acc.z += v * xx.z;
            acc.w += v * xx.w;
        }
    }
    ((float4*)out)[r * 64 + lane] = acc;
}

// ---------------- round-1 proven fallback (minimal ws) ----------------

__global__ void zero_counts_kernel(int* deg, int n) {
    int i = blockIdx.x * blockDim.x + threadIdx.x;
    if (i < n) deg[i] = 0;
}

__global__ void hist_kernel(const int* __restrict__ row, int* __restrict__ deg, int nnz) {
    int stride = gridDim.x * blockDim.x;
    for (int e = blockIdx.x * blockDim.x + threadIdx.x; e < nnz; e += stride) {
        atomicAdd(&deg[row[e]], 1);
    }
}

__global__ void scan_partials_kernel(int* partials, int nb) {
    if (blockIdx.x == 0 && threadIdx.x == 0) {
        int run = 0;
        for (int i = 0; i < nb; ++i) { int v = partials[i]; partials[i] = run; run += v; }
    }
}

__global__ void finalize_scan_cursor_kernel(int* __restrict__ rowstart, const int* __restrict__ partials,
                                            int* __restrict__ cursor, int n, int nnz) {
    int i = blockIdx.x * blockDim.x + threadIdx.x;
    if (i < n) {
        int v = rowstart[i] + partials[i / SCAN_CHUNK];
        rowstart[i] = v;
        cursor[i] = v;
    }
    if (i == 0) rowstart[n] = nnz;
}

__global__ void scatter_eperm_kernel(const int* __restrict__ row, int* __restrict__ cursor,
                                     int* __restrict__ eperm, int nnz) {
    int stride = gridDim.x * blockDim.x;
    for (int e = blockIdx.x * blockDim.x + threadIdx.x; e < nnz; e += stride) {
        int p = atomicAdd(&cursor[row[e]], 1);
        eperm[p] = e;
    }
}

__global__ __launch_bounds__(256) void spmm_eperm_kernel(const float* __restrict__ x,
                                                         const float* __restrict__ vals,
                                                         const int* __restrict__ col,
                                                         const int* __restrict__ rowstart,
                                                         const int* __restrict__ eperm,
                                                         float* __restrict__ out, int n) {
    const int wave = threadIdx.x >> 6;
    const int lane = threadIdx.x & 63;
    const int r = blockIdx.x * 4 + wave;
    if (r >= n) return;
    const int s = rowstart[r];
    const int e = rowstart[r + 1];
    const float4* __restrict__ xv = (const float4*)x;
    float4 acc = make_float4(0.f, 0.f, 0.f, 0.f);
    for (int k0 = s; k0 < e; k0 += 64) {
        int cnt = e - k0; if (cnt > 64) cnt = 64;
        float myv = 0.f; int myc = 0;
        if (lane < cnt) {
            int ed = eperm[k0 + lane];
            myv = vals[ed];
            myc = col[ed];
        }
        for (int j = 0; j < cnt; ++j) {
            float v = __shfl(myv, j);
            int   c = __shfl(myc, j);
            float4 xx = xv[c * 64 + lane];
            acc.x += v * xx.x;
            acc.y += v * xx.y;
            acc.z += v * xx.z;
            acc.w += v * xx.w;
        }
    }
    ((float4*)out)[r * 64 + lane] = acc;
}

// ---------------- launch ----------------

extern "C" void kernel_launch(void* const* d_in, const int* in_sizes, int n_in,
                              void* d_out, int out_size, void* d_ws, size_t ws_size,
                              hipStream_t stream) {
    const float* x    = (const float*)d_in[0];
    const float* vals = (const float*)d_in[1];
    const int*   row  = (const int*)d_in[2];
    const int*   col  = (const int*)d_in[3];
    float* out = (float*)d_out;

    const int nnz = in_sizes[1];
    const int n   = out_size / FEAT;
    const int nb  = (n + SCAN_CHUNK - 1) / SCAN_CHUNK;

    // ---- workspace layout (paths A/B) ----
    char* p0 = (char*)d_ws;
    char* p = p0;
    int* deg      = (int*)p; p += (size_t)n * 4;
    int* rowstart = (int*)p; p += (size_t)(n + 1) * 4;
    int* partials = (int*)p; p += 64 * 4;
    int* rank     = (int*)p; p += (size_t)nnz * 4;
    p = (char*)((((size_t)p) + 7) & ~(size_t)7);
    int2* pack    = (int2*)p; p += (size_t)nnz * 8;
    unsigned short* xh = (unsigned short*)p; p += (size_t)n * FEAT * 2;
    const size_t needA = (size_t)(p - p0);
    const size_t needB = needA - (size_t)n * FEAT * 2;

    if (ws_size >= needB) {
        const bool bf = (ws_size >= needA);
        hipMemsetAsync(deg, 0, (size_t)n * 4, stream);
        hist_rank_kernel<<<2048, 256, 0, stream>>>(row, deg, rank, nnz);
        if (bf) convx_kernel<<<2048, 256, 0, stream>>>((const float4*)x, (ushort4*)xh, n * (FEAT / 4));
        scan_chunks_kernel<<<nb, 256, 0, stream>>>(deg, rowstart, partials, n);
        finalize_scan_kernel<<<(n + 255) / 256, 256, 0, stream>>>(rowstart, partials, n, nnz);
        scatter_pack_kernel<<<2048, 256, 0, stream>>>(row, rank, col, vals, rowstart, pack, nnz);
        if (bf)
            spmm_bf16_kernel<<<(n + 3) / 4, 256, 0, stream>>>((const ushort4*)xh, pack, rowstart, out, n);
        else
            spmm_f32_kernel<<<(n + 3) / 4, 256, 0, stream>>>((const float4*)x, pack, rowstart, out, n);
    } else {
        // ---- round-1 proven minimal-ws path ----
        int* degC      = (int*)d_ws;          // n
        int* rowstartC = degC + n;            // n + 1
        int* cursorC   = rowstartC + (n + 1); // n
        int* partialsC = cursorC + n;         // 64
        int* epermC    = partialsC + 64;      // nnz

        zero_counts_kernel<<<(n + 255) / 256, 256, 0, stream>>>(degC, n);
        hist_kernel<<<2048, 256, 0, stream>>>(row, degC, nnz);
        scan_chunks_kernel<<<nb, 256, 0, stream>>>(degC, rowstartC, partialsC, n);
        scan_partials_kernel<<<1, 64, 0, stream>>>(partialsC, nb);
        finalize_scan_cursor_kernel<<<(n + 255) / 256, 256, 0, stream>>>(rowstartC, partialsC, cursorC, n, nnz);
        scatter_eperm_kernel<<<2048, 256, 0, stream>>>(row, cursorC, epermC, nnz);
        spmm_eperm_kernel<<<(n + 3) / 4, 256, 0, stream>>>(x, vals, col, rowstartC, epermC, out, n);
    }
}